// Round 5
// baseline (373.658 us; speedup 1.0000x reference)
//
#include <hip/hip_runtime.h>
#include <math.h>

static constexpr int N = 50000;
static constexpr int E = 800000;
static constexpr int D = 128;      // D_IN = D_HID
static constexpr int DO = 64;      // D_OUT
static constexpr int NB = (N + 255) / 256;   // 196 scan blocks

// ---------------- degree+count histogram (packed u64 atomic) ----------------
// packed[i] = (cnt << 48) | sum_fix48(ew * 2^31)

__global__ __launch_bounds__(256) void k_hist(const int* __restrict__ dst,
                                              const float* __restrict__ ew,
                                              unsigned long long* __restrict__ packed) {
  int e = blockIdx.x * 256 + threadIdx.x;
  if (e < E) {
    unsigned wfix = (unsigned)(ew[e] * 2147483648.0f + 0.5f);
    unsigned long long inc = (1ULL << 48) | (unsigned long long)wfix;
    __hip_atomic_fetch_add(&packed[dst[e]], inc, __ATOMIC_RELAXED, __HIP_MEMORY_SCOPE_AGENT);
  }
}

// scan stage 1 fused with finalize: unpack cnt+deg, write dinv & cnt(->cursor),
// and produce per-block count sums
__global__ __launch_bounds__(256) void k_scan1(const unsigned long long* __restrict__ packed,
                                               float* __restrict__ dinv,
                                               int* __restrict__ cnt_out,
                                               int* __restrict__ partial) {
  __shared__ int sm[256];
  int i = blockIdx.x * 256 + threadIdx.x;
  int t = threadIdx.x;
  int c = 0;
  if (i < N) {
    unsigned long long v = packed[i];
    c = (int)(v >> 48);
    float deg = 1.0f + (float)((double)(v & 0x0000FFFFFFFFFFFFULL) * (1.0 / 2147483648.0));
    dinv[i] = 1.0f / sqrtf(deg);
    cnt_out[i] = c;
  }
  sm[t] = c;
  __syncthreads();
#pragma unroll
  for (int off = 128; off > 0; off >>= 1) {
    if (t < off) sm[t] += sm[t + off];
    __syncthreads();
  }
  if (t == 0) partial[blockIdx.x] = sm[0];
}

__global__ __launch_bounds__(256) void k_scan2(int* __restrict__ partial) {
  __shared__ int sm[256];
  int t = threadIdx.x;
  int v = (t < NB) ? partial[t] : 0;
  sm[t] = v;
  __syncthreads();
#pragma unroll
  for (int off = 1; off < 256; off <<= 1) {
    int u = (t >= off) ? sm[t - off] : 0;
    __syncthreads();
    sm[t] += u;
    __syncthreads();
  }
  if (t < NB) partial[t] = sm[t] - v;   // exclusive block offsets
}

// cnt_in aliases `cursor`; each thread re-writes cursor[i] after reading it
__global__ __launch_bounds__(256) void k_scan3(const int* __restrict__ cnt_in,
                                               const int* __restrict__ partial,
                                               int* __restrict__ rowptr,
                                               int* __restrict__ cursor) {
  __shared__ int sm[256];
  int i = blockIdx.x * 256 + threadIdx.x;
  int t = threadIdx.x;
  int v = (i < N) ? cnt_in[i] : 0;
  sm[t] = v;
  __syncthreads();
#pragma unroll
  for (int off = 1; off < 256; off <<= 1) {
    int u = (t >= off) ? sm[t - off] : 0;
    __syncthreads();
    sm[t] += u;
    __syncthreads();
  }
  int excl = sm[t] - v + partial[blockIdx.x];
  if (i < N) { rowptr[i] = excl; cursor[i] = excl; }
  if (i == N) rowptr[N] = E;
}

// scatter edges into CSR order (packed int2: src, float_bits(norm))
__global__ __launch_bounds__(256) void k_build_csr(const int* __restrict__ src,
                                                   const int* __restrict__ dst,
                                                   const float* __restrict__ ew,
                                                   const float* __restrict__ dinv,
                                                   int* __restrict__ cursor,
                                                   int2* __restrict__ csr) {
  int e = blockIdx.x * 256 + threadIdx.x;
  if (e >= E) return;
  int s = src[e], d = dst[e];
  float w = dinv[s] * ew[e] * dinv[d];
  int pos = __hip_atomic_fetch_add(&cursor[d], 1, __ATOMIC_RELAXED, __HIP_MEMORY_SCOPE_AGENT);
  csr[pos] = make_int2(s, __float_as_int(w));
}

// ---------------- aggregation: out[i] = sum_{e->i} h[src]*w + h[i]*dinv[i]^2 ----------------
// one 64-lane wave per node; lane owns float2 of the 128-dim row; 16x edge unroll
__global__ __launch_bounds__(256) void k_aggregate(const float* __restrict__ h,
                                                   const int* __restrict__ rowptr,
                                                   const int2* __restrict__ csr,
                                                   const float* __restrict__ dinv,
                                                   float* __restrict__ out) {
  int node = blockIdx.x * 4 + (threadIdx.x >> 6);
  if (node >= N) return;
  int lane = threadIdx.x & 63;
  const float* hp = h + (size_t)lane * 2;

  float s = dinv[node];
  float s2 = s * s;
  float2 hv = *(const float2*)(hp + (size_t)node * D);
  float ax = hv.x * s2, ay = hv.y * s2;

  int e = rowptr[node];
  int end = rowptr[node + 1];

  // peel to even e so int4 (16B) loads on csr are aligned
  if ((e & 1) && e < end) {
    int2 pe = csr[e];
    float w = __int_as_float(pe.y);
    float2 v = *(const float2*)(hp + (size_t)pe.x * D);
    ax = fmaf(v.x, w, ax); ay = fmaf(v.y, w, ay);
    ++e;
  }
  // 16-edge blocks: 8 csr int4 loads then 16 independent gathers in flight
  for (; e + 16 <= end; e += 16) {
    int4 pp[8];
#pragma unroll
    for (int j = 0; j < 8; ++j) pp[j] = *(const int4*)(csr + e + 2 * j);
    float2 v[16];
#pragma unroll
    for (int j = 0; j < 8; ++j) {
      v[2 * j + 0] = *(const float2*)(hp + (size_t)pp[j].x * D);
      v[2 * j + 1] = *(const float2*)(hp + (size_t)pp[j].z * D);
    }
#pragma unroll
    for (int j = 0; j < 8; ++j) {
      float w0 = __int_as_float(pp[j].y);
      float w1 = __int_as_float(pp[j].w);
      ax = fmaf(v[2 * j + 0].x, w0, ax); ay = fmaf(v[2 * j + 0].y, w0, ay);
      ax = fmaf(v[2 * j + 1].x, w1, ax); ay = fmaf(v[2 * j + 1].y, w1, ay);
    }
  }
  // one 8-edge block for the remainder
  if (e + 8 <= end) {
    int4 pp[4];
#pragma unroll
    for (int j = 0; j < 4; ++j) pp[j] = *(const int4*)(csr + e + 2 * j);
    float2 v[8];
#pragma unroll
    for (int j = 0; j < 4; ++j) {
      v[2 * j + 0] = *(const float2*)(hp + (size_t)pp[j].x * D);
      v[2 * j + 1] = *(const float2*)(hp + (size_t)pp[j].z * D);
    }
#pragma unroll
    for (int j = 0; j < 4; ++j) {
      float w0 = __int_as_float(pp[j].y);
      float w1 = __int_as_float(pp[j].w);
      ax = fmaf(v[2 * j + 0].x, w0, ax); ay = fmaf(v[2 * j + 0].y, w0, ay);
      ax = fmaf(v[2 * j + 1].x, w1, ax); ay = fmaf(v[2 * j + 1].y, w1, ay);
    }
    e += 8;
  }
  for (; e + 2 <= end; e += 2) {
    int4 p0 = *(const int4*)(csr + e);
    float2 v0 = *(const float2*)(hp + (size_t)p0.x * D);
    float2 v1 = *(const float2*)(hp + (size_t)p0.z * D);
    float w0 = __int_as_float(p0.y), w1 = __int_as_float(p0.w);
    ax = fmaf(v0.x, w0, ax); ay = fmaf(v0.y, w0, ay);
    ax = fmaf(v1.x, w1, ax); ay = fmaf(v1.y, w1, ay);
  }
  if (e < end) {
    int2 pe = csr[e];
    float w = __int_as_float(pe.y);
    float2 v = *(const float2*)(hp + (size_t)pe.x * D);
    ax = fmaf(v.x, w, ax); ay = fmaf(v.y, w, ay);
  }
  float2 r; r.x = ax; r.y = ay;
  *(float2*)(out + (size_t)node * D + lane * 2) = r;
}

// ---------------- GEMM: out[N,128] = A[N,128] @ W[128,128] + bias (opt relu) ----------------

template <bool RELU>
__global__ __launch_bounds__(256) void k_gemm_bias(const float* __restrict__ A,
                                                   const float* __restrict__ W,
                                                   const float* __restrict__ bias,
                                                   float* __restrict__ out) {
  __shared__ __align__(16) float Wl[128][128];
  __shared__ __align__(16) float Al[32][128];
  const int tid = threadIdx.x;

  {
    const float4* W4 = (const float4*)W;
    float4* Wl4 = (float4*)&Wl[0][0];
#pragma unroll
    for (int i = 0; i < 16; ++i) Wl4[tid + i * 256] = W4[tid + i * 256];
  }
  const int row0 = blockIdx.x * 32;
  {
    const float4* A4 = (const float4*)(A + (size_t)row0 * D);
    float4* Al4 = (float4*)&Al[0][0];
#pragma unroll
    for (int i = 0; i < 4; ++i) {
      int idx = tid + i * 256;
      int r = idx >> 5;
      float4 v = make_float4(0.f, 0.f, 0.f, 0.f);
      if (row0 + r < N) v = A4[idx];
      Al4[idx] = v;
    }
  }
  __syncthreads();

  const int c0 = (tid & 31) * 4;
  const int r0 = (tid >> 5) * 4;
  float acc[4][4] = {};
  for (int k4 = 0; k4 < 32; ++k4) {
    float4 a[4];
#pragma unroll
    for (int r = 0; r < 4; ++r) a[r] = *(const float4*)&Al[r0 + r][k4 * 4];
    float4 w[4];
#pragma unroll
    for (int kk = 0; kk < 4; ++kk) w[kk] = *(const float4*)&Wl[k4 * 4 + kk][c0];
#pragma unroll
    for (int r = 0; r < 4; ++r) {
      float av0 = a[r].x, av1 = a[r].y, av2 = a[r].z, av3 = a[r].w;
#pragma unroll
      for (int cc = 0; cc < 4; ++cc) {
        float wv0 = (&w[0].x)[cc], wv1 = (&w[1].x)[cc], wv2 = (&w[2].x)[cc], wv3 = (&w[3].x)[cc];
        float v = acc[r][cc];
        v = fmaf(av0, wv0, v);
        v = fmaf(av1, wv1, v);
        v = fmaf(av2, wv2, v);
        v = fmaf(av3, wv3, v);
        acc[r][cc] = v;
      }
    }
  }
  float4 b = *(const float4*)&bias[c0];
#pragma unroll
  for (int r = 0; r < 4; ++r) {
    int row = row0 + r0 + r;
    if (row < N) {
      float4 v;
      v.x = acc[r][0] + b.x; v.y = acc[r][1] + b.y;
      v.z = acc[r][2] + b.z; v.w = acc[r][3] + b.w;
      if (RELU) {
        v.x = fmaxf(v.x, 0.f); v.y = fmaxf(v.y, 0.f);
        v.z = fmaxf(v.z, 0.f); v.w = fmaxf(v.w, 0.f);
      }
      *(float4*)&out[(size_t)row * D + c0] = v;
    }
  }
}

// heads: cols 0-63 -> mu = A@Wmu+bmu, cols 64-127 -> std = A@Wstd+bstd
__global__ __launch_bounds__(256) void k_gemm_dual(const float* __restrict__ A,
                                                   const float* __restrict__ Wmu,
                                                   const float* __restrict__ Wstd,
                                                   const float* __restrict__ bmu,
                                                   const float* __restrict__ bstd,
                                                   float* __restrict__ out) {
  __shared__ __align__(16) float Wl[128][128];
  __shared__ __align__(16) float Al[32][128];
  const int tid = threadIdx.x;

  {
    const float4* Wm4 = (const float4*)Wmu;
    const float4* Ws4 = (const float4*)Wstd;
#pragma unroll
    for (int i = 0; i < 8; ++i) {
      int idx = tid + i * 256;
      int k = idx >> 4;
      int c4 = idx & 15;
      *(float4*)&Wl[k][c4 * 4] = Wm4[idx];
      *(float4*)&Wl[k][64 + c4 * 4] = Ws4[idx];
    }
  }
  const int row0 = blockIdx.x * 32;
  {
    const float4* A4 = (const float4*)(A + (size_t)row0 * D);
    float4* Al4 = (float4*)&Al[0][0];
#pragma unroll
    for (int i = 0; i < 4; ++i) {
      int idx = tid + i * 256;
      int r = idx >> 5;
      float4 v = make_float4(0.f, 0.f, 0.f, 0.f);
      if (row0 + r < N) v = A4[idx];
      Al4[idx] = v;
    }
  }
  __syncthreads();

  const int c0 = (tid & 31) * 4;
  const int r0 = (tid >> 5) * 4;
  float acc[4][4] = {};
  for (int k4 = 0; k4 < 32; ++k4) {
    float4 a[4];
#pragma unroll
    for (int r = 0; r < 4; ++r) a[r] = *(const float4*)&Al[r0 + r][k4 * 4];
    float4 w[4];
#pragma unroll
    for (int kk = 0; kk < 4; ++kk) w[kk] = *(const float4*)&Wl[k4 * 4 + kk][c0];
#pragma unroll
    for (int r = 0; r < 4; ++r) {
      float av0 = a[r].x, av1 = a[r].y, av2 = a[r].z, av3 = a[r].w;
#pragma unroll
      for (int cc = 0; cc < 4; ++cc) {
        float wv0 = (&w[0].x)[cc], wv1 = (&w[1].x)[cc], wv2 = (&w[2].x)[cc], wv3 = (&w[3].x)[cc];
        float v = acc[r][cc];
        v = fmaf(av0, wv0, v);
        v = fmaf(av1, wv1, v);
        v = fmaf(av2, wv2, v);
        v = fmaf(av3, wv3, v);
        acc[r][cc] = v;
      }
    }
  }
  const bool is_mu = (c0 < DO);
  const int cc0 = is_mu ? c0 : (c0 - DO);
  const float* bsel = is_mu ? bmu : bstd;
  float4 b = *(const float4*)&bsel[cc0];
  float* base = is_mu ? out : (out + (size_t)N * DO);
#pragma unroll
  for (int r = 0; r < 4; ++r) {
    int row = row0 + r0 + r;
    if (row < N) {
      float4 v;
      v.x = acc[r][0] + b.x; v.y = acc[r][1] + b.y;
      v.z = acc[r][2] + b.z; v.w = acc[r][3] + b.w;
      *(float4*)&base[(size_t)row * DO + cc0] = v;
    }
  }
}

// ---------------- launcher ----------------

static inline char* align256(char* p) {
  return (char*)(((uintptr_t)p + 255) & ~(uintptr_t)255);
}

extern "C" void kernel_launch(void* const* d_in, const int* in_sizes, int n_in,
                              void* d_out, int out_size, void* d_ws, size_t ws_size,
                              hipStream_t stream) {
  const float* x    = (const float*)d_in[0];
  const int*   ei   = (const int*)d_in[1];     // [2, E] int32
  const float* ew   = (const float*)d_in[2];
  const float* W1   = (const float*)d_in[3];
  const float* b1   = (const float*)d_in[4];
  const float* W2   = (const float*)d_in[5];
  const float* b2   = (const float*)d_in[6];
  const float* Wmu  = (const float*)d_in[7];
  const float* bmu  = (const float*)d_in[8];
  const float* Wstd = (const float*)d_in[9];
  const float* bstd = (const float*)d_in[10];
  float* out = (float*)d_out;

  const int* srcI = ei;
  const int* dstI = ei + E;

  char* p = (char*)d_ws;
  float* dinv    = (float*)p;            p = align256(p + (size_t)N * 4);
  int*   rowptr  = (int*)p;              p = align256(p + (size_t)(N + 1) * 4);
  int*   cursor  = (int*)p;              p = align256(p + (size_t)N * 4);
  int*   partial = (int*)p;              p = align256(p + (size_t)256 * 4);
  int2*  csr     = (int2*)p;             p = align256(p + (size_t)E * 8);
  float* buf0    = (float*)p;            p = align256(p + (size_t)N * D * 4);
  float* buf1    = (float*)p;
  // packed u64 histogram aliases buf0 (consumed before buf0 is first written)
  unsigned long long* packed = (unsigned long long*)buf0;

  dim3 blk(256);
  const int gN1  = (N + 256) / 256;      // covers i == N in scan3
  const int gE   = (E + 255) / 256;
  const int gAgg = (N + 3) / 4;
  const int gGemm = (N + 31) / 32;

  // CSR + norm precompute (once per call)
  hipMemsetAsync(packed, 0, (size_t)N * 8, stream);
  k_hist<<<gE, blk, 0, stream>>>(dstI, ew, packed);
  k_scan1<<<NB, blk, 0, stream>>>(packed, dinv, cursor, partial);  // finalize fused
  k_scan2<<<1, blk, 0, stream>>>(partial);
  k_scan3<<<gN1, blk, 0, stream>>>(cursor, partial, rowptr, cursor);
  k_build_csr<<<gE, blk, 0, stream>>>(srcI, dstI, ew, dinv, cursor, csr);

  // layer 1: h1 = relu(A(x) @ W1 + b1)
  k_aggregate<<<gAgg, blk, 0, stream>>>(x, rowptr, csr, dinv, buf0);
  k_gemm_bias<true><<<gGemm, blk, 0, stream>>>(buf0, W1, b1, buf1);

  // layer 2: h2 = relu(A(h1) @ W2 + b2)
  k_aggregate<<<gAgg, blk, 0, stream>>>(buf1, rowptr, csr, dinv, buf0);
  k_gemm_bias<true><<<gGemm, blk, 0, stream>>>(buf0, W2, b2, buf1);

  // heads: one shared aggregation, two output projections
  k_aggregate<<<gAgg, blk, 0, stream>>>(buf1, rowptr, csr, dinv, buf0);
  k_gemm_dual<<<gGemm, blk, 0, stream>>>(buf0, Wmu, Wstd, bmu, bstd, out);
}

// Round 6
// 280.362 us; speedup vs baseline: 1.3328x; 1.3328x over previous
//
#include <hip/hip_runtime.h>
#include <math.h>

static constexpr int N = 50000;
static constexpr int E = 800000;
static constexpr int D = 128;      // D_IN = D_HID
static constexpr int DO = 64;      // D_OUT
static constexpr int NB = (N + 255) / 256;   // 196 scan blocks

// ---- bf16x2 packing (RNE) ----
__device__ __forceinline__ unsigned pack_bf16(float a, float b) {
  unsigned ua = __float_as_uint(a), ub = __float_as_uint(b);
  ua = (ua + 0x7FFFu + ((ua >> 16) & 1u)) >> 16;
  ub = (ub + 0x7FFFu + ((ub >> 16) & 1u)) >> 16;
  return ua | (ub << 16);
}

// ---------------- degree+count histogram (packed u64 atomic) ----------------
// packed[i] = (cnt << 48) | sum_fix48(ew * 2^31); returns per-dst slot in pos[e]

__global__ __launch_bounds__(256) void k_hist(const int* __restrict__ dst,
                                              const float* __restrict__ ew,
                                              unsigned long long* __restrict__ packed,
                                              int* __restrict__ pos) {
  int e = blockIdx.x * 256 + threadIdx.x;
  if (e < E) {
    unsigned wfix = (unsigned)(ew[e] * 2147483648.0f + 0.5f);
    unsigned long long inc = (1ULL << 48) | (unsigned long long)wfix;
    unsigned long long old =
        __hip_atomic_fetch_add(&packed[dst[e]], inc, __ATOMIC_RELAXED, __HIP_MEMORY_SCOPE_AGENT);
    pos[e] = (int)(old >> 48);
  }
}

// scan stage 1 fused with finalize: unpack cnt+deg, write dinv & cnt, block sums
__global__ __launch_bounds__(256) void k_scan1(const unsigned long long* __restrict__ packed,
                                               float* __restrict__ dinv,
                                               int* __restrict__ cnt_out,
                                               int* __restrict__ partial) {
  __shared__ int sm[256];
  int i = blockIdx.x * 256 + threadIdx.x;
  int t = threadIdx.x;
  int c = 0;
  if (i < N) {
    unsigned long long v = packed[i];
    c = (int)(v >> 48);
    float deg = 1.0f + (float)((double)(v & 0x0000FFFFFFFFFFFFULL) * (1.0 / 2147483648.0));
    dinv[i] = 1.0f / sqrtf(deg);
    cnt_out[i] = c;
  }
  sm[t] = c;
  __syncthreads();
#pragma unroll
  for (int off = 128; off > 0; off >>= 1) {
    if (t < off) sm[t] += sm[t + off];
    __syncthreads();
  }
  if (t == 0) partial[blockIdx.x] = sm[0];
}

__global__ __launch_bounds__(256) void k_scan2(int* __restrict__ partial) {
  __shared__ int sm[256];
  int t = threadIdx.x;
  int v = (t < NB) ? partial[t] : 0;
  sm[t] = v;
  __syncthreads();
#pragma unroll
  for (int off = 1; off < 256; off <<= 1) {
    int u = (t >= off) ? sm[t - off] : 0;
    __syncthreads();
    sm[t] += u;
    __syncthreads();
  }
  if (t < NB) partial[t] = sm[t] - v;   // exclusive block offsets
}

__global__ __launch_bounds__(256) void k_scan3(const int* __restrict__ cnt_in,
                                               const int* __restrict__ partial,
                                               int* __restrict__ rowptr) {
  __shared__ int sm[256];
  int i = blockIdx.x * 256 + threadIdx.x;
  int t = threadIdx.x;
  int v = (i < N) ? cnt_in[i] : 0;
  sm[t] = v;
  __syncthreads();
#pragma unroll
  for (int off = 1; off < 256; off <<= 1) {
    int u = (t >= off) ? sm[t - off] : 0;
    __syncthreads();
    sm[t] += u;
    __syncthreads();
  }
  int excl = sm[t] - v + partial[blockIdx.x];
  if (i < N) rowptr[i] = excl;
  if (i == N) rowptr[N] = E;
}

// place edges into CSR order without atomics: slot = rowptr[dst] + pos[e]
__global__ __launch_bounds__(256) void k_build_csr(const int* __restrict__ src,
                                                   const int* __restrict__ dst,
                                                   const float* __restrict__ ew,
                                                   const float* __restrict__ dinv,
                                                   const int* __restrict__ rowptr,
                                                   const int* __restrict__ pos,
                                                   int2* __restrict__ csr) {
  int e = blockIdx.x * 256 + threadIdx.x;
  if (e >= E) return;
  int s = src[e], d = dst[e];
  float w = dinv[s] * ew[e] * dinv[d];
  int p = rowptr[d] + pos[e];
  csr[p] = make_int2(s, __float_as_int(w));
}

// ---------------- cast x -> packed bf16 ----------------
__global__ __launch_bounds__(256) void k_cast(const float* __restrict__ x,
                                              unsigned* __restrict__ outb) {
  int g = blockIdx.x * 256 + threadIdx.x;   // over N*64
  if (g < N * 64) {
    float2 v = ((const float2*)x)[g];
    outb[g] = pack_bf16(v.x, v.y);
  }
}

// ---------------- aggregation (bf16 gather, fp32 accumulate) ----------------
// out[i] = sum_{e->i} bh[src]*w + bh[i]*dinv[i]^2 ; one wave per node,
// lane owns dims (2*lane, 2*lane+1) = one packed uint; 8x edge unroll
__global__ __launch_bounds__(256) void k_aggregate(const unsigned* __restrict__ bh,
                                                   const int* __restrict__ rowptr,
                                                   const int2* __restrict__ csr,
                                                   const float* __restrict__ dinv,
                                                   float* __restrict__ out) {
  int node = blockIdx.x * 4 + (threadIdx.x >> 6);
  if (node >= N) return;
  int lane = threadIdx.x & 63;
  const unsigned* bp = bh + lane;

  float s = dinv[node];
  float s2 = s * s;
  unsigned hb = bp[(size_t)node * 64];
  float ax = __uint_as_float(hb << 16) * s2;
  float ay = __uint_as_float(hb & 0xFFFF0000u) * s2;

  int e = rowptr[node];
  int end = rowptr[node + 1];

  // peel to even e so int4 (16B) loads on csr are aligned
  if ((e & 1) && e < end) {
    int2 pe = csr[e];
    float w = __int_as_float(pe.y);
    unsigned b = bp[(size_t)pe.x * 64];
    ax = fmaf(__uint_as_float(b << 16), w, ax);
    ay = fmaf(__uint_as_float(b & 0xFFFF0000u), w, ay);
    ++e;
  }
  for (; e + 8 <= end; e += 8) {
    int4 p0 = *(const int4*)(csr + e + 0);
    int4 p1 = *(const int4*)(csr + e + 2);
    int4 p2 = *(const int4*)(csr + e + 4);
    int4 p3 = *(const int4*)(csr + e + 6);
    unsigned b0 = bp[(size_t)p0.x * 64];
    unsigned b1 = bp[(size_t)p0.z * 64];
    unsigned b2 = bp[(size_t)p1.x * 64];
    unsigned b3 = bp[(size_t)p1.z * 64];
    unsigned b4 = bp[(size_t)p2.x * 64];
    unsigned b5 = bp[(size_t)p2.z * 64];
    unsigned b6 = bp[(size_t)p3.x * 64];
    unsigned b7 = bp[(size_t)p3.z * 64];
    float w0 = __int_as_float(p0.y), w1 = __int_as_float(p0.w);
    float w2 = __int_as_float(p1.y), w3 = __int_as_float(p1.w);
    float w4 = __int_as_float(p2.y), w5 = __int_as_float(p2.w);
    float w6 = __int_as_float(p3.y), w7 = __int_as_float(p3.w);
    ax = fmaf(__uint_as_float(b0 << 16), w0, ax); ay = fmaf(__uint_as_float(b0 & 0xFFFF0000u), w0, ay);
    ax = fmaf(__uint_as_float(b1 << 16), w1, ax); ay = fmaf(__uint_as_float(b1 & 0xFFFF0000u), w1, ay);
    ax = fmaf(__uint_as_float(b2 << 16), w2, ax); ay = fmaf(__uint_as_float(b2 & 0xFFFF0000u), w2, ay);
    ax = fmaf(__uint_as_float(b3 << 16), w3, ax); ay = fmaf(__uint_as_float(b3 & 0xFFFF0000u), w3, ay);
    ax = fmaf(__uint_as_float(b4 << 16), w4, ax); ay = fmaf(__uint_as_float(b4 & 0xFFFF0000u), w4, ay);
    ax = fmaf(__uint_as_float(b5 << 16), w5, ax); ay = fmaf(__uint_as_float(b5 & 0xFFFF0000u), w5, ay);
    ax = fmaf(__uint_as_float(b6 << 16), w6, ax); ay = fmaf(__uint_as_float(b6 & 0xFFFF0000u), w6, ay);
    ax = fmaf(__uint_as_float(b7 << 16), w7, ax); ay = fmaf(__uint_as_float(b7 & 0xFFFF0000u), w7, ay);
  }
  for (; e + 2 <= end; e += 2) {
    int4 p0 = *(const int4*)(csr + e);
    unsigned b0 = bp[(size_t)p0.x * 64];
    unsigned b1 = bp[(size_t)p0.z * 64];
    float w0 = __int_as_float(p0.y), w1 = __int_as_float(p0.w);
    ax = fmaf(__uint_as_float(b0 << 16), w0, ax); ay = fmaf(__uint_as_float(b0 & 0xFFFF0000u), w0, ay);
    ax = fmaf(__uint_as_float(b1 << 16), w1, ax); ay = fmaf(__uint_as_float(b1 & 0xFFFF0000u), w1, ay);
  }
  if (e < end) {
    int2 pe = csr[e];
    float w = __int_as_float(pe.y);
    unsigned b = bp[(size_t)pe.x * 64];
    ax = fmaf(__uint_as_float(b << 16), w, ax);
    ay = fmaf(__uint_as_float(b & 0xFFFF0000u), w, ay);
  }
  float2 r; r.x = ax; r.y = ay;
  *(float2*)(out + (size_t)node * D + lane * 2) = r;
}

// ---------------- GEMM: relu(A@W+b) -> packed bf16 ----------------
__global__ __launch_bounds__(256) void k_gemm_relu_bf16(const float* __restrict__ A,
                                                        const float* __restrict__ W,
                                                        const float* __restrict__ bias,
                                                        unsigned* __restrict__ outb) {
  __shared__ __align__(16) float Wl[128][128];
  __shared__ __align__(16) float Al[32][128];
  const int tid = threadIdx.x;

  {
    const float4* W4 = (const float4*)W;
    float4* Wl4 = (float4*)&Wl[0][0];
#pragma unroll
    for (int i = 0; i < 16; ++i) Wl4[tid + i * 256] = W4[tid + i * 256];
  }
  const int row0 = blockIdx.x * 32;
  {
    const float4* A4 = (const float4*)(A + (size_t)row0 * D);
    float4* Al4 = (float4*)&Al[0][0];
#pragma unroll
    for (int i = 0; i < 4; ++i) {
      int idx = tid + i * 256;
      int r = idx >> 5;
      float4 v = make_float4(0.f, 0.f, 0.f, 0.f);
      if (row0 + r < N) v = A4[idx];
      Al4[idx] = v;
    }
  }
  __syncthreads();

  const int c0 = (tid & 31) * 4;
  const int r0 = (tid >> 5) * 4;
  float acc[4][4] = {};
  for (int k4 = 0; k4 < 32; ++k4) {
    float4 a[4];
#pragma unroll
    for (int r = 0; r < 4; ++r) a[r] = *(const float4*)&Al[r0 + r][k4 * 4];
    float4 w[4];
#pragma unroll
    for (int kk = 0; kk < 4; ++kk) w[kk] = *(const float4*)&Wl[k4 * 4 + kk][c0];
#pragma unroll
    for (int r = 0; r < 4; ++r) {
      float av0 = a[r].x, av1 = a[r].y, av2 = a[r].z, av3 = a[r].w;
#pragma unroll
      for (int cc = 0; cc < 4; ++cc) {
        float wv0 = (&w[0].x)[cc], wv1 = (&w[1].x)[cc], wv2 = (&w[2].x)[cc], wv3 = (&w[3].x)[cc];
        float v = acc[r][cc];
        v = fmaf(av0, wv0, v);
        v = fmaf(av1, wv1, v);
        v = fmaf(av2, wv2, v);
        v = fmaf(av3, wv3, v);
        acc[r][cc] = v;
      }
    }
  }
  float4 b = *(const float4*)&bias[c0];
#pragma unroll
  for (int r = 0; r < 4; ++r) {
    int row = row0 + r0 + r;
    if (row < N) {
      float v0 = fmaxf(acc[r][0] + b.x, 0.f);
      float v1 = fmaxf(acc[r][1] + b.y, 0.f);
      float v2 = fmaxf(acc[r][2] + b.z, 0.f);
      float v3 = fmaxf(acc[r][3] + b.w, 0.f);
      uint2 u;
      u.x = pack_bf16(v0, v1);
      u.y = pack_bf16(v2, v3);
      *(uint2*)&outb[(size_t)row * 64 + (c0 >> 1)] = u;
    }
  }
}

// heads: cols 0-63 -> mu = A@Wmu+bmu, cols 64-127 -> std = A@Wstd+bstd (fp32 out)
__global__ __launch_bounds__(256) void k_gemm_dual(const float* __restrict__ A,
                                                   const float* __restrict__ Wmu,
                                                   const float* __restrict__ Wstd,
                                                   const float* __restrict__ bmu,
                                                   const float* __restrict__ bstd,
                                                   float* __restrict__ out) {
  __shared__ __align__(16) float Wl[128][128];
  __shared__ __align__(16) float Al[32][128];
  const int tid = threadIdx.x;

  {
    const float4* Wm4 = (const float4*)Wmu;
    const float4* Ws4 = (const float4*)Wstd;
#pragma unroll
    for (int i = 0; i < 8; ++i) {
      int idx = tid + i * 256;
      int k = idx >> 4;
      int c4 = idx & 15;
      *(float4*)&Wl[k][c4 * 4] = Wm4[idx];
      *(float4*)&Wl[k][64 + c4 * 4] = Ws4[idx];
    }
  }
  const int row0 = blockIdx.x * 32;
  {
    const float4* A4 = (const float4*)(A + (size_t)row0 * D);
    float4* Al4 = (float4*)&Al[0][0];
#pragma unroll
    for (int i = 0; i < 4; ++i) {
      int idx = tid + i * 256;
      int r = idx >> 5;
      float4 v = make_float4(0.f, 0.f, 0.f, 0.f);
      if (row0 + r < N) v = A4[idx];
      Al4[idx] = v;
    }
  }
  __syncthreads();

  const int c0 = (tid & 31) * 4;
  const int r0 = (tid >> 5) * 4;
  float acc[4][4] = {};
  for (int k4 = 0; k4 < 32; ++k4) {
    float4 a[4];
#pragma unroll
    for (int r = 0; r < 4; ++r) a[r] = *(const float4*)&Al[r0 + r][k4 * 4];
    float4 w[4];
#pragma unroll
    for (int kk = 0; kk < 4; ++kk) w[kk] = *(const float4*)&Wl[k4 * 4 + kk][c0];
#pragma unroll
    for (int r = 0; r < 4; ++r) {
      float av0 = a[r].x, av1 = a[r].y, av2 = a[r].z, av3 = a[r].w;
#pragma unroll
      for (int cc = 0; cc < 4; ++cc) {
        float wv0 = (&w[0].x)[cc], wv1 = (&w[1].x)[cc], wv2 = (&w[2].x)[cc], wv3 = (&w[3].x)[cc];
        float v = acc[r][cc];
        v = fmaf(av0, wv0, v);
        v = fmaf(av1, wv1, v);
        v = fmaf(av2, wv2, v);
        v = fmaf(av3, wv3, v);
        acc[r][cc] = v;
      }
    }
  }
  const bool is_mu = (c0 < DO);
  const int cc0 = is_mu ? c0 : (c0 - DO);
  const float* bsel = is_mu ? bmu : bstd;
  float4 b = *(const float4*)&bsel[cc0];
  float* base = is_mu ? out : (out + (size_t)N * DO);
#pragma unroll
  for (int r = 0; r < 4; ++r) {
    int row = row0 + r0 + r;
    if (row < N) {
      float4 v;
      v.x = acc[r][0] + b.x; v.y = acc[r][1] + b.y;
      v.z = acc[r][2] + b.z; v.w = acc[r][3] + b.w;
      *(float4*)&base[(size_t)row * DO + cc0] = v;
    }
  }
}

// ---------------- launcher ----------------

static inline char* align256(char* p) {
  return (char*)(((uintptr_t)p + 255) & ~(uintptr_t)255);
}

extern "C" void kernel_launch(void* const* d_in, const int* in_sizes, int n_in,
                              void* d_out, int out_size, void* d_ws, size_t ws_size,
                              hipStream_t stream) {
  const float* x    = (const float*)d_in[0];
  const int*   ei   = (const int*)d_in[1];     // [2, E] int32
  const float* ew   = (const float*)d_in[2];
  const float* W1   = (const float*)d_in[3];
  const float* b1   = (const float*)d_in[4];
  const float* W2   = (const float*)d_in[5];
  const float* b2   = (const float*)d_in[6];
  const float* Wmu  = (const float*)d_in[7];
  const float* bmu  = (const float*)d_in[8];
  const float* Wstd = (const float*)d_in[9];
  const float* bstd = (const float*)d_in[10];
  float* out = (float*)d_out;

  const int* srcI = ei;
  const int* dstI = ei + E;

  char* p = (char*)d_ws;
  float*    dinv    = (float*)p;     p = align256(p + (size_t)N * 4);
  int*      rowptr  = (int*)p;       p = align256(p + (size_t)(N + 1) * 4);
  int*      cnt     = (int*)p;       p = align256(p + (size_t)N * 4);
  int*      partial = (int*)p;       p = align256(p + (size_t)256 * 4);
  int2*     csr     = (int2*)p;      p = align256(p + (size_t)E * 8);
  float*    buf0    = (float*)p;     p = align256(p + (size_t)N * D * 4);  // 25.6 MB
  unsigned* bfh     = (unsigned*)p;  p = align256(p + (size_t)N * 64 * 4); // 12.8 MB
  // transient aliases inside buf0 (all dead before first aggregate writes buf0)
  unsigned long long* packed = (unsigned long long*)buf0;                   // N*8 = 0.4 MB
  int*      pos     = (int*)((char*)buf0 + (1 << 20));                      // E*4 = 3.2 MB

  dim3 blk(256);
  const int gN1   = (N + 256) / 256;      // covers i == N in scan3
  const int gE    = (E + 255) / 256;
  const int gAgg  = (N + 3) / 4;
  const int gGemm = (N + 31) / 32;
  const int gCast = (N * 64 + 255) / 256;

  // CSR + norm precompute (once per call)
  hipMemsetAsync(packed, 0, (size_t)N * 8, stream);
  k_hist<<<gE, blk, 0, stream>>>(dstI, ew, packed, pos);
  k_scan1<<<NB, blk, 0, stream>>>(packed, dinv, cnt, partial);
  k_scan2<<<1, blk, 0, stream>>>(partial);
  k_scan3<<<gN1, blk, 0, stream>>>(cnt, partial, rowptr);
  k_build_csr<<<gE, blk, 0, stream>>>(srcI, dstI, ew, dinv, rowptr, pos, csr);

  // cast input features to packed bf16
  k_cast<<<gCast, blk, 0, stream>>>(x, bfh);

  // layer 1: h1 = relu(A(x) @ W1 + b1)   (bfh: x -> h1)
  k_aggregate<<<gAgg, blk, 0, stream>>>(bfh, rowptr, csr, dinv, buf0);
  k_gemm_relu_bf16<<<gGemm, blk, 0, stream>>>(buf0, W1, b1, bfh);

  // layer 2: h2 = relu(A(h1) @ W2 + b2)  (bfh: h1 -> h2)
  k_aggregate<<<gAgg, blk, 0, stream>>>(bfh, rowptr, csr, dinv, buf0);
  k_gemm_relu_bf16<<<gGemm, blk, 0, stream>>>(buf0, W2, b2, bfh);

  // heads: one shared aggregation, two output projections
  k_aggregate<<<gAgg, blk, 0, stream>>>(bfh, rowptr, csr, dinv, buf0);
  k_gemm_dual<<<gGemm, blk, 0, stream>>>(buf0, Wmu, Wstd, bmu, bstd, out);
}

// Round 7
// 278.761 us; speedup vs baseline: 1.3404x; 1.0057x over previous
//
#include <hip/hip_runtime.h>
#include <math.h>

static constexpr int N = 50000;
static constexpr int E = 800000;
static constexpr int D = 128;      // D_IN = D_HID
static constexpr int DO = 64;      // D_OUT
static constexpr int NB = (N + 255) / 256;   // 196 scan blocks

// ---- bf16x2 packing (RNE) ----
__device__ __forceinline__ unsigned pack_bf16(float a, float b) {
  unsigned ua = __float_as_uint(a), ub = __float_as_uint(b);
  ua = (ua + 0x7FFFu + ((ua >> 16) & 1u)) >> 16;
  ub = (ub + 0x7FFFu + ((ub >> 16) & 1u)) >> 16;
  return ua | (ub << 16);
}

// ---------------- init (replaces 40us runtime fillBuffer) ----------------
__global__ __launch_bounds__(256) void k_init(unsigned long long* __restrict__ packed) {
  int i = blockIdx.x * 256 + threadIdx.x;
  if (i < N) packed[i] = 0ULL;
}

// ---------------- degree+count histogram (packed u64 atomic) ----------------
// packed[i] = (cnt << 48) | sum_fix48(ew * 2^31); returns per-dst slot in pos[e]

__global__ __launch_bounds__(256) void k_hist(const int* __restrict__ dst,
                                              const float* __restrict__ ew,
                                              unsigned long long* __restrict__ packed,
                                              int* __restrict__ pos) {
  int e = blockIdx.x * 256 + threadIdx.x;
  if (e < E) {
    unsigned wfix = (unsigned)(ew[e] * 2147483648.0f + 0.5f);
    unsigned long long inc = (1ULL << 48) | (unsigned long long)wfix;
    unsigned long long old =
        __hip_atomic_fetch_add(&packed[dst[e]], inc, __ATOMIC_RELAXED, __HIP_MEMORY_SCOPE_AGENT);
    pos[e] = (int)(old >> 48);
  }
}

// scan stage 1 fused with finalize: unpack cnt+deg, write dinv & cnt, block sums
__global__ __launch_bounds__(256) void k_scan1(const unsigned long long* __restrict__ packed,
                                               float* __restrict__ dinv,
                                               int* __restrict__ cnt_out,
                                               int* __restrict__ partial) {
  __shared__ int sm[256];
  int i = blockIdx.x * 256 + threadIdx.x;
  int t = threadIdx.x;
  int c = 0;
  if (i < N) {
    unsigned long long v = packed[i];
    c = (int)(v >> 48);
    float deg = 1.0f + (float)((double)(v & 0x0000FFFFFFFFFFFFULL) * (1.0 / 2147483648.0));
    dinv[i] = 1.0f / sqrtf(deg);
    cnt_out[i] = c;
  }
  sm[t] = c;
  __syncthreads();
#pragma unroll
  for (int off = 128; off > 0; off >>= 1) {
    if (t < off) sm[t] += sm[t + off];
    __syncthreads();
  }
  if (t == 0) partial[blockIdx.x] = sm[0];
}

// scan3 with fused block-offset reduction (no separate scan2 pass)
__global__ __launch_bounds__(256) void k_scan3(const int* __restrict__ cnt_in,
                                               const int* __restrict__ partial,
                                               int* __restrict__ rowptr) {
  __shared__ int sm[256];
  __shared__ int blkoff;
  int i = blockIdx.x * 256 + threadIdx.x;
  int t = threadIdx.x;

  // block offset = sum of partial[0 .. blockIdx-1]
  sm[t] = (t < blockIdx.x && t < NB) ? partial[t] : 0;
  __syncthreads();
#pragma unroll
  for (int off = 128; off > 0; off >>= 1) {
    if (t < off) sm[t] += sm[t + off];
    __syncthreads();
  }
  if (t == 0) blkoff = sm[0];
  __syncthreads();

  int v = (i < N) ? cnt_in[i] : 0;
  sm[t] = v;
  __syncthreads();
#pragma unroll
  for (int off = 1; off < 256; off <<= 1) {
    int u = (t >= off) ? sm[t - off] : 0;
    __syncthreads();
    sm[t] += u;
    __syncthreads();
  }
  int excl = sm[t] - v + blkoff;
  if (i < N) rowptr[i] = excl;
  if (i == N) rowptr[N] = E;
}

// place edges into CSR order without atomics: slot = rowptr[dst] + pos[e]
__global__ __launch_bounds__(256) void k_build_csr(const int* __restrict__ src,
                                                   const int* __restrict__ dst,
                                                   const float* __restrict__ ew,
                                                   const float* __restrict__ dinv,
                                                   const int* __restrict__ rowptr,
                                                   const int* __restrict__ pos,
                                                   int2* __restrict__ csr) {
  int e = blockIdx.x * 256 + threadIdx.x;
  if (e >= E) return;
  int s = src[e], d = dst[e];
  float w = dinv[s] * ew[e] * dinv[d];
  int p = rowptr[d] + pos[e];
  csr[p] = make_int2(s, __float_as_int(w));
}

// ---------------- cast x -> packed bf16 ----------------
__global__ __launch_bounds__(256) void k_cast(const float* __restrict__ x,
                                              unsigned* __restrict__ outb) {
  int g = blockIdx.x * 256 + threadIdx.x;   // over N*64
  if (g < N * 64) {
    float2 v = ((const float2*)x)[g];
    outb[g] = pack_bf16(v.x, v.y);
  }
}

// ---------------- aggregation (bf16 gather, fp32 accumulate) ----------------
// out[i] = sum_{e->i} bh[src]*w + bh[i]*dinv[i]^2 ; one wave per node,
// lane owns dims (2*lane, 2*lane+1) = one packed uint; 8x edge unroll
__global__ __launch_bounds__(256) void k_aggregate(const unsigned* __restrict__ bh,
                                                   const int* __restrict__ rowptr,
                                                   const int2* __restrict__ csr,
                                                   const float* __restrict__ dinv,
                                                   float* __restrict__ out) {
  int node = blockIdx.x * 4 + (threadIdx.x >> 6);
  if (node >= N) return;
  int lane = threadIdx.x & 63;
  const unsigned* bp = bh + lane;

  float s = dinv[node];
  float s2 = s * s;
  unsigned hb = bp[(size_t)node * 64];
  float ax = __uint_as_float(hb << 16) * s2;
  float ay = __uint_as_float(hb & 0xFFFF0000u) * s2;

  int e = rowptr[node];
  int end = rowptr[node + 1];

  // peel to even e so int4 (16B) loads on csr are aligned
  if ((e & 1) && e < end) {
    int2 pe = csr[e];
    float w = __int_as_float(pe.y);
    unsigned b = bp[(size_t)pe.x * 64];
    ax = fmaf(__uint_as_float(b << 16), w, ax);
    ay = fmaf(__uint_as_float(b & 0xFFFF0000u), w, ay);
    ++e;
  }
  for (; e + 8 <= end; e += 8) {
    int4 p0 = *(const int4*)(csr + e + 0);
    int4 p1 = *(const int4*)(csr + e + 2);
    int4 p2 = *(const int4*)(csr + e + 4);
    int4 p3 = *(const int4*)(csr + e + 6);
    unsigned b0 = bp[(size_t)p0.x * 64];
    unsigned b1 = bp[(size_t)p0.z * 64];
    unsigned b2 = bp[(size_t)p1.x * 64];
    unsigned b3 = bp[(size_t)p1.z * 64];
    unsigned b4 = bp[(size_t)p2.x * 64];
    unsigned b5 = bp[(size_t)p2.z * 64];
    unsigned b6 = bp[(size_t)p3.x * 64];
    unsigned b7 = bp[(size_t)p3.z * 64];
    float w0 = __int_as_float(p0.y), w1 = __int_as_float(p0.w);
    float w2 = __int_as_float(p1.y), w3 = __int_as_float(p1.w);
    float w4 = __int_as_float(p2.y), w5 = __int_as_float(p2.w);
    float w6 = __int_as_float(p3.y), w7 = __int_as_float(p3.w);
    ax = fmaf(__uint_as_float(b0 << 16), w0, ax); ay = fmaf(__uint_as_float(b0 & 0xFFFF0000u), w0, ay);
    ax = fmaf(__uint_as_float(b1 << 16), w1, ax); ay = fmaf(__uint_as_float(b1 & 0xFFFF0000u), w1, ay);
    ax = fmaf(__uint_as_float(b2 << 16), w2, ax); ay = fmaf(__uint_as_float(b2 & 0xFFFF0000u), w2, ay);
    ax = fmaf(__uint_as_float(b3 << 16), w3, ax); ay = fmaf(__uint_as_float(b3 & 0xFFFF0000u), w3, ay);
    ax = fmaf(__uint_as_float(b4 << 16), w4, ax); ay = fmaf(__uint_as_float(b4 & 0xFFFF0000u), w4, ay);
    ax = fmaf(__uint_as_float(b5 << 16), w5, ax); ay = fmaf(__uint_as_float(b5 & 0xFFFF0000u), w5, ay);
    ax = fmaf(__uint_as_float(b6 << 16), w6, ax); ay = fmaf(__uint_as_float(b6 & 0xFFFF0000u), w6, ay);
    ax = fmaf(__uint_as_float(b7 << 16), w7, ax); ay = fmaf(__uint_as_float(b7 & 0xFFFF0000u), w7, ay);
  }
  for (; e + 2 <= end; e += 2) {
    int4 p0 = *(const int4*)(csr + e);
    unsigned b0 = bp[(size_t)p0.x * 64];
    unsigned b1 = bp[(size_t)p0.z * 64];
    float w0 = __int_as_float(p0.y), w1 = __int_as_float(p0.w);
    ax = fmaf(__uint_as_float(b0 << 16), w0, ax); ay = fmaf(__uint_as_float(b0 & 0xFFFF0000u), w0, ay);
    ax = fmaf(__uint_as_float(b1 << 16), w1, ax); ay = fmaf(__uint_as_float(b1 & 0xFFFF0000u), w1, ay);
  }
  if (e < end) {
    int2 pe = csr[e];
    float w = __int_as_float(pe.y);
    unsigned b = bp[(size_t)pe.x * 64];
    ax = fmaf(__uint_as_float(b << 16), w, ax);
    ay = fmaf(__uint_as_float(b & 0xFFFF0000u), w, ay);
  }
  float2 r; r.x = ax; r.y = ay;
  *(float2*)(out + (size_t)node * D + lane * 2) = r;
}

// ---------------- GEMM: relu(A@W+b) -> packed bf16 ----------------
__global__ __launch_bounds__(256) void k_gemm_relu_bf16(const float* __restrict__ A,
                                                        const float* __restrict__ W,
                                                        const float* __restrict__ bias,
                                                        unsigned* __restrict__ outb) {
  __shared__ __align__(16) float Wl[128][128];
  __shared__ __align__(16) float Al[32][128];
  const int tid = threadIdx.x;

  {
    const float4* W4 = (const float4*)W;
    float4* Wl4 = (float4*)&Wl[0][0];
#pragma unroll
    for (int i = 0; i < 16; ++i) Wl4[tid + i * 256] = W4[tid + i * 256];
  }
  const int row0 = blockIdx.x * 32;
  {
    const float4* A4 = (const float4*)(A + (size_t)row0 * D);
    float4* Al4 = (float4*)&Al[0][0];
#pragma unroll
    for (int i = 0; i < 4; ++i) {
      int idx = tid + i * 256;
      int r = idx >> 5;
      float4 v = make_float4(0.f, 0.f, 0.f, 0.f);
      if (row0 + r < N) v = A4[idx];
      Al4[idx] = v;
    }
  }
  __syncthreads();

  const int c0 = (tid & 31) * 4;
  const int r0 = (tid >> 5) * 4;
  float acc[4][4] = {};
  for (int k4 = 0; k4 < 32; ++k4) {
    float4 a[4];
#pragma unroll
    for (int r = 0; r < 4; ++r) a[r] = *(const float4*)&Al[r0 + r][k4 * 4];
    float4 w[4];
#pragma unroll
    for (int kk = 0; kk < 4; ++kk) w[kk] = *(const float4*)&Wl[k4 * 4 + kk][c0];
#pragma unroll
    for (int r = 0; r < 4; ++r) {
      float av0 = a[r].x, av1 = a[r].y, av2 = a[r].z, av3 = a[r].w;
#pragma unroll
      for (int cc = 0; cc < 4; ++cc) {
        float wv0 = (&w[0].x)[cc], wv1 = (&w[1].x)[cc], wv2 = (&w[2].x)[cc], wv3 = (&w[3].x)[cc];
        float v = acc[r][cc];
        v = fmaf(av0, wv0, v);
        v = fmaf(av1, wv1, v);
        v = fmaf(av2, wv2, v);
        v = fmaf(av3, wv3, v);
        acc[r][cc] = v;
      }
    }
  }
  float4 b = *(const float4*)&bias[c0];
#pragma unroll
  for (int r = 0; r < 4; ++r) {
    int row = row0 + r0 + r;
    if (row < N) {
      float v0 = fmaxf(acc[r][0] + b.x, 0.f);
      float v1 = fmaxf(acc[r][1] + b.y, 0.f);
      float v2 = fmaxf(acc[r][2] + b.z, 0.f);
      float v3 = fmaxf(acc[r][3] + b.w, 0.f);
      uint2 u;
      u.x = pack_bf16(v0, v1);
      u.y = pack_bf16(v2, v3);
      *(uint2*)&outb[(size_t)row * 64 + (c0 >> 1)] = u;
    }
  }
}

// heads: cols 0-63 -> mu = A@Wmu+bmu, cols 64-127 -> std = A@Wstd+bstd (fp32 out)
__global__ __launch_bounds__(256) void k_gemm_dual(const float* __restrict__ A,
                                                   const float* __restrict__ Wmu,
                                                   const float* __restrict__ Wstd,
                                                   const float* __restrict__ bmu,
                                                   const float* __restrict__ bstd,
                                                   float* __restrict__ out) {
  __shared__ __align__(16) float Wl[128][128];
  __shared__ __align__(16) float Al[32][128];
  const int tid = threadIdx.x;

  {
    const float4* Wm4 = (const float4*)Wmu;
    const float4* Ws4 = (const float4*)Wstd;
#pragma unroll
    for (int i = 0; i < 8; ++i) {
      int idx = tid + i * 256;
      int k = idx >> 4;
      int c4 = idx & 15;
      *(float4*)&Wl[k][c4 * 4] = Wm4[idx];
      *(float4*)&Wl[k][64 + c4 * 4] = Ws4[idx];
    }
  }
  const int row0 = blockIdx.x * 32;
  {
    const float4* A4 = (const float4*)(A + (size_t)row0 * D);
    float4* Al4 = (float4*)&Al[0][0];
#pragma unroll
    for (int i = 0; i < 4; ++i) {
      int idx = tid + i * 256;
      int r = idx >> 5;
      float4 v = make_float4(0.f, 0.f, 0.f, 0.f);
      if (row0 + r < N) v = A4[idx];
      Al4[idx] = v;
    }
  }
  __syncthreads();

  const int c0 = (tid & 31) * 4;
  const int r0 = (tid >> 5) * 4;
  float acc[4][4] = {};
  for (int k4 = 0; k4 < 32; ++k4) {
    float4 a[4];
#pragma unroll
    for (int r = 0; r < 4; ++r) a[r] = *(const float4*)&Al[r0 + r][k4 * 4];
    float4 w[4];
#pragma unroll
    for (int kk = 0; kk < 4; ++kk) w[kk] = *(const float4*)&Wl[k4 * 4 + kk][c0];
#pragma unroll
    for (int r = 0; r < 4; ++r) {
      float av0 = a[r].x, av1 = a[r].y, av2 = a[r].z, av3 = a[r].w;
#pragma unroll
      for (int cc = 0; cc < 4; ++cc) {
        float wv0 = (&w[0].x)[cc], wv1 = (&w[1].x)[cc], wv2 = (&w[2].x)[cc], wv3 = (&w[3].x)[cc];
        float v = acc[r][cc];
        v = fmaf(av0, wv0, v);
        v = fmaf(av1, wv1, v);
        v = fmaf(av2, wv2, v);
        v = fmaf(av3, wv3, v);
        acc[r][cc] = v;
      }
    }
  }
  const bool is_mu = (c0 < DO);
  const int cc0 = is_mu ? c0 : (c0 - DO);
  const float* bsel = is_mu ? bmu : bstd;
  float4 b = *(const float4*)&bsel[cc0];
  float* base = is_mu ? out : (out + (size_t)N * DO);
#pragma unroll
  for (int r = 0; r < 4; ++r) {
    int row = row0 + r0 + r;
    if (row < N) {
      float4 v;
      v.x = acc[r][0] + b.x; v.y = acc[r][1] + b.y;
      v.z = acc[r][2] + b.z; v.w = acc[r][3] + b.w;
      *(float4*)&base[(size_t)row * DO + cc0] = v;
    }
  }
}

// ---------------- launcher ----------------

static inline char* align256(char* p) {
  return (char*)(((uintptr_t)p + 255) & ~(uintptr_t)255);
}

extern "C" void kernel_launch(void* const* d_in, const int* in_sizes, int n_in,
                              void* d_out, int out_size, void* d_ws, size_t ws_size,
                              hipStream_t stream) {
  const float* x    = (const float*)d_in[0];
  const int*   ei   = (const int*)d_in[1];     // [2, E] int32
  const float* ew   = (const float*)d_in[2];
  const float* W1   = (const float*)d_in[3];
  const float* b1   = (const float*)d_in[4];
  const float* W2   = (const float*)d_in[5];
  const float* b2   = (const float*)d_in[6];
  const float* Wmu  = (const float*)d_in[7];
  const float* bmu  = (const float*)d_in[8];
  const float* Wstd = (const float*)d_in[9];
  const float* bstd = (const float*)d_in[10];
  float* out = (float*)d_out;

  const int* srcI = ei;
  const int* dstI = ei + E;

  char* p = (char*)d_ws;
  float*    dinv    = (float*)p;     p = align256(p + (size_t)N * 4);
  int*      rowptr  = (int*)p;       p = align256(p + (size_t)(N + 1) * 4);
  int*      cnt     = (int*)p;       p = align256(p + (size_t)N * 4);
  int*      partial = (int*)p;       p = align256(p + (size_t)256 * 4);
  int2*     csr     = (int2*)p;      p = align256(p + (size_t)E * 8);
  float*    buf0    = (float*)p;     p = align256(p + (size_t)N * D * 4);  // 25.6 MB
  unsigned* bfh     = (unsigned*)p;  p = align256(p + (size_t)N * 64 * 4); // 12.8 MB
  // transient aliases inside buf0 (all dead before first aggregate writes buf0)
  unsigned long long* packed = (unsigned long long*)buf0;                   // N*8 = 0.4 MB
  int*      pos     = (int*)((char*)buf0 + (1 << 20));                      // E*4 = 3.2 MB

  dim3 blk(256);
  const int gN1   = (N + 256) / 256;      // covers i == N in scan3
  const int gE    = (E + 255) / 256;
  const int gAgg  = (N + 3) / 4;
  const int gGemm = (N + 31) / 32;
  const int gCast = (N * 64 + 255) / 256;

  // CSR + norm precompute (once per call)
  k_init<<<NB, blk, 0, stream>>>(packed);
  k_hist<<<gE, blk, 0, stream>>>(dstI, ew, packed, pos);
  k_scan1<<<NB, blk, 0, stream>>>(packed, dinv, cnt, partial);
  k_scan3<<<gN1, blk, 0, stream>>>(cnt, partial, rowptr);
  k_build_csr<<<gE, blk, 0, stream>>>(srcI, dstI, ew, dinv, rowptr, pos, csr);

  // cast input features to packed bf16
  k_cast<<<gCast, blk, 0, stream>>>(x, bfh);

  // layer 1: h1 = relu(A(x) @ W1 + b1)   (bfh: x -> h1)
  k_aggregate<<<gAgg, blk, 0, stream>>>(bfh, rowptr, csr, dinv, buf0);
  k_gemm_relu_bf16<<<gGemm, blk, 0, stream>>>(buf0, W1, b1, bfh);

  // layer 2: h2 = relu(A(h1) @ W2 + b2)  (bfh: h1 -> h2)
  k_aggregate<<<gAgg, blk, 0, stream>>>(bfh, rowptr, csr, dinv, buf0);
  k_gemm_relu_bf16<<<gGemm, blk, 0, stream>>>(buf0, W2, b2, bfh);

  // heads: one shared aggregation, two output projections
  k_aggregate<<<gAgg, blk, 0, stream>>>(bfh, rowptr, csr, dinv, buf0);
  k_gemm_dual<<<gGemm, blk, 0, stream>>>(buf0, Wmu, Wstd, bmu, bstd, out);
}

// Round 8
// 275.597 us; speedup vs baseline: 1.3558x; 1.0115x over previous
//
#include <hip/hip_runtime.h>
#include <math.h>

static constexpr int N = 50000;
static constexpr int E = 800000;
static constexpr int D = 128;      // D_IN = D_HID
static constexpr int DO = 64;      // D_OUT
static constexpr int NB = (N + 255) / 256;   // 196 scan blocks
static constexpr int KSH = 8;                // histogram shards

// ---- bf16x2 packing (RNE) ----
__device__ __forceinline__ unsigned pack_bf16(float a, float b) {
  unsigned ua = __float_as_uint(a), ub = __float_as_uint(b);
  ua = (ua + 0x7FFFu + ((ua >> 16) & 1u)) >> 16;
  ub = (ub + 0x7FFFu + ((ub >> 16) & 1u)) >> 16;
  return ua | (ub << 16);
}

// ---------------- prep: zero sharded histogram + cast x -> packed bf16 ----------------
__global__ __launch_bounds__(256) void k_prep(const float* __restrict__ x,
                                              unsigned* __restrict__ outb,
                                              unsigned long long* __restrict__ packed_sh) {
  int g = blockIdx.x * 256 + threadIdx.x;   // over N*64
  if (g < N * 64) {
    float2 v = ((const float2*)x)[g];
    outb[g] = pack_bf16(v.x, v.y);
  }
  if (g < KSH * N) packed_sh[g] = 0ULL;
}

// ---------------- sharded degree+count histogram ----------------
// packed_sh[k][i] = (cnt << 48) | sum_fix48(ew * 2^31); pos[e] = per-shard slot

__global__ __launch_bounds__(256) void k_hist(const int* __restrict__ dst,
                                              const float* __restrict__ ew,
                                              unsigned long long* __restrict__ packed_sh,
                                              int* __restrict__ pos) {
  int e = blockIdx.x * 256 + threadIdx.x;
  if (e < E) {
    int k = (e >> 8) & (KSH - 1);
    unsigned wfix = (unsigned)(ew[e] * 2147483648.0f + 0.5f);
    unsigned long long inc = (1ULL << 48) | (unsigned long long)wfix;
    unsigned long long old = __hip_atomic_fetch_add(&packed_sh[(size_t)k * N + dst[e]], inc,
                                                    __ATOMIC_RELAXED, __HIP_MEMORY_SCOPE_AGENT);
    pos[e] = (int)(old >> 48);
  }
}

// fold shards: dinv, total cnt, per-shard exclusive bases, block partial sums
__global__ __launch_bounds__(256) void k_scan1(const unsigned long long* __restrict__ packed_sh,
                                               float* __restrict__ dinv,
                                               int* __restrict__ cnt_out,
                                               int* __restrict__ shard_base,
                                               int* __restrict__ partial) {
  __shared__ int sm[256];
  int i = blockIdx.x * 256 + threadIdx.x;
  int t = threadIdx.x;
  int c = 0;
  if (i < N) {
    unsigned long long wtot = 0;
    int run = 0;
#pragma unroll
    for (int k = 0; k < KSH; ++k) {
      unsigned long long v = packed_sh[(size_t)k * N + i];
      shard_base[(size_t)k * N + i] = run;
      run += (int)(v >> 48);
      wtot += (v & 0x0000FFFFFFFFFFFFULL);
    }
    c = run;
    float deg = 1.0f + (float)((double)wtot * (1.0 / 2147483648.0));
    dinv[i] = 1.0f / sqrtf(deg);
    cnt_out[i] = c;
  }
  sm[t] = c;
  __syncthreads();
#pragma unroll
  for (int off = 128; off > 0; off >>= 1) {
    if (t < off) sm[t] += sm[t + off];
    __syncthreads();
  }
  if (t == 0) partial[blockIdx.x] = sm[0];
}

// scan3 with fused block-offset reduction
__global__ __launch_bounds__(256) void k_scan3(const int* __restrict__ cnt_in,
                                               const int* __restrict__ partial,
                                               int* __restrict__ rowptr) {
  __shared__ int sm[256];
  __shared__ int blkoff;
  int i = blockIdx.x * 256 + threadIdx.x;
  int t = threadIdx.x;

  sm[t] = (t < blockIdx.x && t < NB) ? partial[t] : 0;
  __syncthreads();
#pragma unroll
  for (int off = 128; off > 0; off >>= 1) {
    if (t < off) sm[t] += sm[t + off];
    __syncthreads();
  }
  if (t == 0) blkoff = sm[0];
  __syncthreads();

  int v = (i < N) ? cnt_in[i] : 0;
  sm[t] = v;
  __syncthreads();
#pragma unroll
  for (int off = 1; off < 256; off <<= 1) {
    int u = (t >= off) ? sm[t - off] : 0;
    __syncthreads();
    sm[t] += u;
    __syncthreads();
  }
  int excl = sm[t] - v + blkoff;
  if (i < N) rowptr[i] = excl;
  if (i == N) rowptr[N] = E;
}

// place edges into CSR order, atomic-free:
// slot = rowptr[dst] + shard_base[shard(e)][dst] + pos[e]
__global__ __launch_bounds__(256) void k_build_csr(const int* __restrict__ src,
                                                   const int* __restrict__ dst,
                                                   const float* __restrict__ ew,
                                                   const float* __restrict__ dinv,
                                                   const int* __restrict__ rowptr,
                                                   const int* __restrict__ shard_base,
                                                   const int* __restrict__ pos,
                                                   int2* __restrict__ csr) {
  int e = blockIdx.x * 256 + threadIdx.x;
  if (e >= E) return;
  int k = (e >> 8) & (KSH - 1);
  int s = src[e], d = dst[e];
  float w = dinv[s] * ew[e] * dinv[d];
  int p = rowptr[d] + shard_base[(size_t)k * N + d] + pos[e];
  csr[p] = make_int2(s, __float_as_int(w));
}

// ---------------- aggregation (bf16 gather, fp32 accumulate) ----------------
__global__ __launch_bounds__(256) void k_aggregate(const unsigned* __restrict__ bh,
                                                   const int* __restrict__ rowptr,
                                                   const int2* __restrict__ csr,
                                                   const float* __restrict__ dinv,
                                                   float* __restrict__ out) {
  int node = blockIdx.x * 4 + (threadIdx.x >> 6);
  if (node >= N) return;
  int lane = threadIdx.x & 63;
  const unsigned* bp = bh + lane;

  float s = dinv[node];
  float s2 = s * s;
  unsigned hb = bp[(size_t)node * 64];
  float ax = __uint_as_float(hb << 16) * s2;
  float ay = __uint_as_float(hb & 0xFFFF0000u) * s2;

  int e = rowptr[node];
  int end = rowptr[node + 1];

  if ((e & 1) && e < end) {
    int2 pe = csr[e];
    float w = __int_as_float(pe.y);
    unsigned b = bp[(size_t)pe.x * 64];
    ax = fmaf(__uint_as_float(b << 16), w, ax);
    ay = fmaf(__uint_as_float(b & 0xFFFF0000u), w, ay);
    ++e;
  }
  for (; e + 8 <= end; e += 8) {
    int4 p0 = *(const int4*)(csr + e + 0);
    int4 p1 = *(const int4*)(csr + e + 2);
    int4 p2 = *(const int4*)(csr + e + 4);
    int4 p3 = *(const int4*)(csr + e + 6);
    unsigned b0 = bp[(size_t)p0.x * 64];
    unsigned b1 = bp[(size_t)p0.z * 64];
    unsigned b2 = bp[(size_t)p1.x * 64];
    unsigned b3 = bp[(size_t)p1.z * 64];
    unsigned b4 = bp[(size_t)p2.x * 64];
    unsigned b5 = bp[(size_t)p2.z * 64];
    unsigned b6 = bp[(size_t)p3.x * 64];
    unsigned b7 = bp[(size_t)p3.z * 64];
    float w0 = __int_as_float(p0.y), w1 = __int_as_float(p0.w);
    float w2 = __int_as_float(p1.y), w3 = __int_as_float(p1.w);
    float w4 = __int_as_float(p2.y), w5 = __int_as_float(p2.w);
    float w6 = __int_as_float(p3.y), w7 = __int_as_float(p3.w);
    ax = fmaf(__uint_as_float(b0 << 16), w0, ax); ay = fmaf(__uint_as_float(b0 & 0xFFFF0000u), w0, ay);
    ax = fmaf(__uint_as_float(b1 << 16), w1, ax); ay = fmaf(__uint_as_float(b1 & 0xFFFF0000u), w1, ay);
    ax = fmaf(__uint_as_float(b2 << 16), w2, ax); ay = fmaf(__uint_as_float(b2 & 0xFFFF0000u), w2, ay);
    ax = fmaf(__uint_as_float(b3 << 16), w3, ax); ay = fmaf(__uint_as_float(b3 & 0xFFFF0000u), w3, ay);
    ax = fmaf(__uint_as_float(b4 << 16), w4, ax); ay = fmaf(__uint_as_float(b4 & 0xFFFF0000u), w4, ay);
    ax = fmaf(__uint_as_float(b5 << 16), w5, ax); ay = fmaf(__uint_as_float(b5 & 0xFFFF0000u), w5, ay);
    ax = fmaf(__uint_as_float(b6 << 16), w6, ax); ay = fmaf(__uint_as_float(b6 & 0xFFFF0000u), w6, ay);
    ax = fmaf(__uint_as_float(b7 << 16), w7, ax); ay = fmaf(__uint_as_float(b7 & 0xFFFF0000u), w7, ay);
  }
  for (; e + 2 <= end; e += 2) {
    int4 p0 = *(const int4*)(csr + e);
    unsigned b0 = bp[(size_t)p0.x * 64];
    unsigned b1 = bp[(size_t)p0.z * 64];
    float w0 = __int_as_float(p0.y), w1 = __int_as_float(p0.w);
    ax = fmaf(__uint_as_float(b0 << 16), w0, ax); ay = fmaf(__uint_as_float(b0 & 0xFFFF0000u), w0, ay);
    ax = fmaf(__uint_as_float(b1 << 16), w1, ax); ay = fmaf(__uint_as_float(b1 & 0xFFFF0000u), w1, ay);
  }
  if (e < end) {
    int2 pe = csr[e];
    float w = __int_as_float(pe.y);
    unsigned b = bp[(size_t)pe.x * 64];
    ax = fmaf(__uint_as_float(b << 16), w, ax);
    ay = fmaf(__uint_as_float(b & 0xFFFF0000u), w, ay);
  }
  float2 r; r.x = ax; r.y = ay;
  *(float2*)(out + (size_t)node * D + lane * 2) = r;
}

// ---------------- GEMM: relu(A@W+b) -> packed bf16 ----------------
__global__ __launch_bounds__(256) void k_gemm_relu_bf16(const float* __restrict__ A,
                                                        const float* __restrict__ W,
                                                        const float* __restrict__ bias,
                                                        unsigned* __restrict__ outb) {
  __shared__ __align__(16) float Wl[128][128];
  __shared__ __align__(16) float Al[32][128];
  const int tid = threadIdx.x;

  {
    const float4* W4 = (const float4*)W;
    float4* Wl4 = (float4*)&Wl[0][0];
#pragma unroll
    for (int i = 0; i < 16; ++i) Wl4[tid + i * 256] = W4[tid + i * 256];
  }
  const int row0 = blockIdx.x * 32;
  {
    const float4* A4 = (const float4*)(A + (size_t)row0 * D);
    float4* Al4 = (float4*)&Al[0][0];
#pragma unroll
    for (int i = 0; i < 4; ++i) {
      int idx = tid + i * 256;
      int r = idx >> 5;
      float4 v = make_float4(0.f, 0.f, 0.f, 0.f);
      if (row0 + r < N) v = A4[idx];
      Al4[idx] = v;
    }
  }
  __syncthreads();

  const int c0 = (tid & 31) * 4;
  const int r0 = (tid >> 5) * 4;
  float acc[4][4] = {};
  for (int k4 = 0; k4 < 32; ++k4) {
    float4 a[4];
#pragma unroll
    for (int r = 0; r < 4; ++r) a[r] = *(const float4*)&Al[r0 + r][k4 * 4];
    float4 w[4];
#pragma unroll
    for (int kk = 0; kk < 4; ++kk) w[kk] = *(const float4*)&Wl[k4 * 4 + kk][c0];
#pragma unroll
    for (int r = 0; r < 4; ++r) {
      float av0 = a[r].x, av1 = a[r].y, av2 = a[r].z, av3 = a[r].w;
#pragma unroll
      for (int cc = 0; cc < 4; ++cc) {
        float wv0 = (&w[0].x)[cc], wv1 = (&w[1].x)[cc], wv2 = (&w[2].x)[cc], wv3 = (&w[3].x)[cc];
        float v = acc[r][cc];
        v = fmaf(av0, wv0, v);
        v = fmaf(av1, wv1, v);
        v = fmaf(av2, wv2, v);
        v = fmaf(av3, wv3, v);
        acc[r][cc] = v;
      }
    }
  }
  float4 b = *(const float4*)&bias[c0];
#pragma unroll
  for (int r = 0; r < 4; ++r) {
    int row = row0 + r0 + r;
    if (row < N) {
      float v0 = fmaxf(acc[r][0] + b.x, 0.f);
      float v1 = fmaxf(acc[r][1] + b.y, 0.f);
      float v2 = fmaxf(acc[r][2] + b.z, 0.f);
      float v3 = fmaxf(acc[r][3] + b.w, 0.f);
      uint2 u;
      u.x = pack_bf16(v0, v1);
      u.y = pack_bf16(v2, v3);
      *(uint2*)&outb[(size_t)row * 64 + (c0 >> 1)] = u;
    }
  }
}

// heads: cols 0-63 -> mu, cols 64-127 -> std (fp32 out)
__global__ __launch_bounds__(256) void k_gemm_dual(const float* __restrict__ A,
                                                   const float* __restrict__ Wmu,
                                                   const float* __restrict__ Wstd,
                                                   const float* __restrict__ bmu,
                                                   const float* __restrict__ bstd,
                                                   float* __restrict__ out) {
  __shared__ __align__(16) float Wl[128][128];
  __shared__ __align__(16) float Al[32][128];
  const int tid = threadIdx.x;

  {
    const float4* Wm4 = (const float4*)Wmu;
    const float4* Ws4 = (const float4*)Wstd;
#pragma unroll
    for (int i = 0; i < 8; ++i) {
      int idx = tid + i * 256;
      int k = idx >> 4;
      int c4 = idx & 15;
      *(float4*)&Wl[k][c4 * 4] = Wm4[idx];
      *(float4*)&Wl[k][64 + c4 * 4] = Ws4[idx];
    }
  }
  const int row0 = blockIdx.x * 32;
  {
    const float4* A4 = (const float4*)(A + (size_t)row0 * D);
    float4* Al4 = (float4*)&Al[0][0];
#pragma unroll
    for (int i = 0; i < 4; ++i) {
      int idx = tid + i * 256;
      int r = idx >> 5;
      float4 v = make_float4(0.f, 0.f, 0.f, 0.f);
      if (row0 + r < N) v = A4[idx];
      Al4[idx] = v;
    }
  }
  __syncthreads();

  const int c0 = (tid & 31) * 4;
  const int r0 = (tid >> 5) * 4;
  float acc[4][4] = {};
  for (int k4 = 0; k4 < 32; ++k4) {
    float4 a[4];
#pragma unroll
    for (int r = 0; r < 4; ++r) a[r] = *(const float4*)&Al[r0 + r][k4 * 4];
    float4 w[4];
#pragma unroll
    for (int kk = 0; kk < 4; ++kk) w[kk] = *(const float4*)&Wl[k4 * 4 + kk][c0];
#pragma unroll
    for (int r = 0; r < 4; ++r) {
      float av0 = a[r].x, av1 = a[r].y, av2 = a[r].z, av3 = a[r].w;
#pragma unroll
      for (int cc = 0; cc < 4; ++cc) {
        float wv0 = (&w[0].x)[cc], wv1 = (&w[1].x)[cc], wv2 = (&w[2].x)[cc], wv3 = (&w[3].x)[cc];
        float v = acc[r][cc];
        v = fmaf(av0, wv0, v);
        v = fmaf(av1, wv1, v);
        v = fmaf(av2, wv2, v);
        v = fmaf(av3, wv3, v);
        acc[r][cc] = v;
      }
    }
  }
  const bool is_mu = (c0 < DO);
  const int cc0 = is_mu ? c0 : (c0 - DO);
  const float* bsel = is_mu ? bmu : bstd;
  float4 b = *(const float4*)&bsel[cc0];
  float* base = is_mu ? out : (out + (size_t)N * DO);
#pragma unroll
  for (int r = 0; r < 4; ++r) {
    int row = row0 + r0 + r;
    if (row < N) {
      float4 v;
      v.x = acc[r][0] + b.x; v.y = acc[r][1] + b.y;
      v.z = acc[r][2] + b.z; v.w = acc[r][3] + b.w;
      *(float4*)&base[(size_t)row * DO + cc0] = v;
    }
  }
}

// ---------------- launcher ----------------

static inline char* align256(char* p) {
  return (char*)(((uintptr_t)p + 255) & ~(uintptr_t)255);
}

extern "C" void kernel_launch(void* const* d_in, const int* in_sizes, int n_in,
                              void* d_out, int out_size, void* d_ws, size_t ws_size,
                              hipStream_t stream) {
  const float* x    = (const float*)d_in[0];
  const int*   ei   = (const int*)d_in[1];     // [2, E] int32
  const float* ew   = (const float*)d_in[2];
  const float* W1   = (const float*)d_in[3];
  const float* b1   = (const float*)d_in[4];
  const float* W2   = (const float*)d_in[5];
  const float* b2   = (const float*)d_in[6];
  const float* Wmu  = (const float*)d_in[7];
  const float* bmu  = (const float*)d_in[8];
  const float* Wstd = (const float*)d_in[9];
  const float* bstd = (const float*)d_in[10];
  float* out = (float*)d_out;

  const int* srcI = ei;
  const int* dstI = ei + E;

  char* p = (char*)d_ws;
  float*    dinv    = (float*)p;     p = align256(p + (size_t)N * 4);
  int*      rowptr  = (int*)p;       p = align256(p + (size_t)(N + 1) * 4);
  int*      cnt     = (int*)p;       p = align256(p + (size_t)N * 4);
  int*      partial = (int*)p;       p = align256(p + (size_t)256 * 4);
  int2*     csr     = (int2*)p;      p = align256(p + (size_t)E * 8);
  float*    buf0    = (float*)p;     p = align256(p + (size_t)N * D * 4);  // 25.6 MB
  unsigned* bfh     = (unsigned*)p;  p = align256(p + (size_t)N * 64 * 4); // 12.8 MB
  // transient aliases inside buf0 (all dead before first aggregate writes buf0)
  int* pos = (int*)buf0;                                                    // E*4   = 3.2 MB
  unsigned long long* packed_sh =
      (unsigned long long*)((char*)buf0 + (4 << 20));                       // KSH*N*8 = 3.2 MB
  int* shard_base = (int*)((char*)buf0 + (12 << 20));                       // KSH*N*4 = 1.6 MB

  dim3 blk(256);
  const int gN1   = (N + 256) / 256;      // covers i == N in scan3
  const int gE    = (E + 255) / 256;
  const int gAgg  = (N + 3) / 4;
  const int gGemm = (N + 31) / 32;
  const int gPrep = (N * 64 + 255) / 256; // covers both N*64 cast and KSH*N zero

  // CSR + norm precompute (once per call)
  k_prep<<<gPrep, blk, 0, stream>>>(x, bfh, packed_sh);
  k_hist<<<gE, blk, 0, stream>>>(dstI, ew, packed_sh, pos);
  k_scan1<<<NB, blk, 0, stream>>>(packed_sh, dinv, cnt, shard_base, partial);
  k_scan3<<<gN1, blk, 0, stream>>>(cnt, partial, rowptr);
  k_build_csr<<<gE, blk, 0, stream>>>(srcI, dstI, ew, dinv, rowptr, shard_base, pos, csr);

  // layer 1: h1 = relu(A(x) @ W1 + b1)   (bfh: x -> h1)
  k_aggregate<<<gAgg, blk, 0, stream>>>(bfh, rowptr, csr, dinv, buf0);
  k_gemm_relu_bf16<<<gGemm, blk, 0, stream>>>(buf0, W1, b1, bfh);

  // layer 2: h2 = relu(A(h1) @ W2 + b2)  (bfh: h1 -> h2)
  k_aggregate<<<gAgg, blk, 0, stream>>>(bfh, rowptr, csr, dinv, buf0);
  k_gemm_relu_bf16<<<gGemm, blk, 0, stream>>>(buf0, W2, b2, bfh);

  // heads: one shared aggregation, two output projections
  k_aggregate<<<gAgg, blk, 0, stream>>>(bfh, rowptr, csr, dinv, buf0);
  k_gemm_dual<<<gGemm, blk, 0, stream>>>(buf0, Wmu, Wstd, bmu, bstd, out);
}